// Round 4
// baseline (2018.624 us; speedup 1.0000x reference)
//
#include <hip/hip_runtime.h>
#include <hip/hip_bf16.h>
#include <stdint.h>

#define D_MODEL 1024
#define VOCAB 50257
#define VP 51200          // padded vocab = NTILES * 256
#define ROWS 4096
#define RB 64             // rows (q) per block
#define VS 4              // vocab splits
#define VH (VP / VS)      // 12800
#define VT 256            // vocab tile per iter
#define ITERS (VH / VT)   // 50
#define NTILES (VS * ITERS) // 200
#define LN_EPS 1e-5f

typedef short s16x4 __attribute__((ext_vector_type(4)));
typedef short s16x8 __attribute__((ext_vector_type(8)));
typedef float f32x4 __attribute__((ext_vector_type(4)));
typedef float f32x16 __attribute__((ext_vector_type(16)));

__device__ __forceinline__ unsigned short f2bf(float f) {
  union { __hip_bfloat16 h; unsigned short u; } cv;
  cv.h = __float2bfloat16(f);
  return cv.u;
}
__device__ __forceinline__ float bf2f(unsigned short u) {
  union { float f; unsigned int i; } c;
  c.i = ((unsigned int)u) << 16;
  return c.f;
}

// ---- pack W [VOCAB][1024] fp32 -> frag-stream bf16 ----
// chunk cid = tile*32768 + s*4096 + ks*64 + l ; 16B chunks
// lane l of frag (tile,s,ks): v = tile*256 + s*32 + (l&31), k = ks*16 + (l>>5)*8
__global__ __launch_bounds__(256) void k_pack_w(const float* __restrict__ wsrc,
                                                unsigned short* __restrict__ wp) {
  const int cid = blockIdx.x * 256 + threadIdx.x;
  const int l = cid & 63;
  const int ks = (cid >> 6) & 63;
  const int s = (cid >> 12) & 7;
  const int tile = cid >> 15;
  const int v = tile * 256 + s * 32 + (l & 31);
  const int k = ks * 16 + (l >> 5) * 8;
  s16x8 o;
  if (v < VOCAB) {
    const f32x4* p = reinterpret_cast<const f32x4*>(wsrc + (size_t)v * D_MODEL + k);
    f32x4 a = p[0], b = p[1];
    o[0]=f2bf(a[0]); o[1]=f2bf(a[1]); o[2]=f2bf(a[2]); o[3]=f2bf(a[3]);
    o[4]=f2bf(b[0]); o[5]=f2bf(b[1]); o[6]=f2bf(b[2]); o[7]=f2bf(b[3]);
  } else {
    #pragma unroll
    for (int i = 0; i < 8; ++i) o[i] = 0;
  }
  reinterpret_cast<s16x8*>(wp)[cid] = o;
}

// ---- pack emb [VOCAB][1024] fp32 -> transposed frag-stream bf16 ----
// chunk cid = tile*32768 + w*2048 + ks2*128 + dt*64 + l  (w:16, ks2:16, dt:2)
// lane l: d = w*64 + dt*32 + (l&31), v = tile*256 + ks2*16 + (l>>5)*8 + j
__global__ __launch_bounds__(256) void k_pack_e(const float* __restrict__ emb,
                                                unsigned short* __restrict__ ep) {
  __shared__ unsigned short tileS[256][33];
  const int tile = blockIdx.x;       // [0,200)
  const int dblk = blockIdx.y;       // [0,32) : d-slice [dblk*32, +32) ; w=dblk>>1, dt=dblk&1
  const int t = threadIdx.x;
  {
    const int v = tile * 256 + t;
    if (v < VOCAB) {
      const f32x4* src = reinterpret_cast<const f32x4*>(emb + (size_t)v * D_MODEL + dblk * 32);
      #pragma unroll
      for (int i = 0; i < 8; ++i) {
        f32x4 a = src[i];
        #pragma unroll
        for (int j = 0; j < 4; ++j) tileS[t][i * 4 + j] = f2bf(a[j]);
      }
    } else {
      #pragma unroll
      for (int i = 0; i < 32; ++i) tileS[t][i] = 0;
    }
  }
  __syncthreads();
  #pragma unroll
  for (int i = 0; i < 4; ++i) {
    const int c = t + i * 256;
    const int l = c & 63;
    const int ks2 = c >> 6;           // [0,16)
    const int dloc = l & 31;
    s16x8 o;
    #pragma unroll
    for (int j = 0; j < 8; ++j) o[j] = tileS[ks2 * 16 + (l >> 5) * 8 + j][dloc];
    const size_t cid = (size_t)tile * 32768 + (size_t)(dblk >> 1) * 2048
                     + (size_t)ks2 * 128 + (size_t)(dblk & 1) * 64 + l;
    reinterpret_cast<s16x8*>(ep)[cid] = o;
  }
}

// ---- pad+convert bias to bf16 [VP] ----
__global__ __launch_bounds__(256) void k_pack_bias(const float* __restrict__ b,
                                                   unsigned short* __restrict__ bp) {
  const int v = blockIdx.x * 256 + threadIdx.x;
  bp[v] = f2bf(v < VOCAB ? b[v] : 0.f);
}

// ---- main fused kernel: 256 blocks (1/CU), 16 waves ----
// phase 1: wave (s=w>>1, qt=w&1) computes S^T tile [32v x 32q] over K=1024
// phase 2: wave w owns d-slice [w*64, +64), both q-tiles
__global__ __launch_bounds__(1024, 4)
void k_main(const float* __restrict__ enc, const unsigned short* __restrict__ biasb,
            const unsigned short* __restrict__ Wp, const unsigned short* __restrict__ Ep,
            float* __restrict__ o_part, float* __restrict__ den_part) {
  __shared__ unsigned short Qf[65536];   // 128 KB frag-ordered Q
  __shared__ unsigned short Pl[16384];   // 32 KB: P[64 q][256 v] bf16, XOR-swizzled

  const int bx = blockIdx.x;
  const int xcd = bx & 7;
  const int vs = xcd & 3;
  const int rb = (xcd >> 2) * 32 + (bx >> 3);   // [0,64)
  const int row0 = rb * RB;
  const int tid = threadIdx.x;
  const int w = tid >> 6;          // 0..15
  const int l = tid & 63;
  const int l31 = l & 31;
  const int lh = l >> 5;
  const int s = w >> 1;            // phase-1 v-stripe
  const int qt = w & 1;            // phase-1 q-tile
  const int q = qt * 32 + l31;     // phase-1 D col / P row

  // ---- stage Q frag-ordered: frag (qtt,ks) lane ((kc&1)<<5)|(q&31) ----
  for (int c = tid; c < RB * 128; c += 1024) {
    const int qq = c >> 7;
    const int kc = c & 127;
    const f32x4* src = reinterpret_cast<const f32x4*>(enc + (size_t)(row0 + qq) * D_MODEL + kc * 8);
    f32x4 a = src[0], b = src[1];
    s16x8 o;
    o[0]=f2bf(a[0]); o[1]=f2bf(a[1]); o[2]=f2bf(a[2]); o[3]=f2bf(a[3]);
    o[4]=f2bf(b[0]); o[5]=f2bf(b[1]); o[6]=f2bf(b[2]); o[7]=f2bf(b[3]);
    const int qtt = qq >> 5, ks = kc >> 1, lane = ((kc & 1) << 5) | (qq & 31);
    reinterpret_cast<s16x8*>(Qf)[(qtt * 64 + ks) * 64 + lane] = o;
  }
  __syncthreads();

  const s16x8* QvV = reinterpret_cast<const s16x8*>(Qf) + (size_t)(qt * 64) * 64 + l;
  char* PlB = reinterpret_cast<char*>(Pl);
  const uint32_t swzq = (uint32_t)(q & 15) << 4;
  const uint32_t swzr = (uint32_t)(l31 & 15) << 4;

  float den = 0.f;
  f32x16 Oa0, Oa1, Ob0, Ob1;
  #pragma unroll
  for (int i = 0; i < 16; ++i) { Oa0[i] = 0.f; Oa1[i] = 0.f; Ob0[i] = 0.f; Ob1[i] = 0.f; }

  for (int it = 0; it < ITERS; ++it) {
    const int tile = vs * ITERS + it;

    // hoisted bias loads (consumed after barrier A; hidden under phase 1)
    const unsigned short* bb = biasb + tile * 256 + s * 32 + 4 * lh;
    const s16x4 b0 = *reinterpret_cast<const s16x4*>(bb);
    const s16x4 b1 = *reinterpret_cast<const s16x4*>(bb + 8);
    const s16x4 b2 = *reinterpret_cast<const s16x4*>(bb + 16);
    const s16x4 b3 = *reinterpret_cast<const s16x4*>(bb + 24);

    // ---- phase 1: S^T = W.Q^T, fully unrolled stream ----
    f32x16 S;
    #pragma unroll
    for (int i = 0; i < 16; ++i) S[i] = 0.f;
    const s16x8* wv = reinterpret_cast<const s16x8*>(Wp) + (size_t)tile * 32768 + s * 4096 + l;
    #pragma unroll
    for (int ks = 0; ks < 64; ++ks) {
      S = __builtin_amdgcn_mfma_f32_32x32x16_bf16(wv[ks * 64], QvV[(size_t)ks * 64], S, 0, 0, 0);
    }
    __syncthreads();  // barrier A: all phase-2 reads of Pl(it-1) done

    // E prefetch for ks2=0 (independent of P)
    const s16x8* ev = reinterpret_cast<const s16x8*>(Ep) + (size_t)tile * 32768 + w * 2048 + l;
    const s16x8 e00 = ev[0];
    const s16x8 e01 = ev[64];

    // ---- exp + bias + P write + denom (all 16 waves) ----
    {
      const int vbase = tile * 256 + s * 32 + 4 * lh;
      #pragma unroll
      for (int m = 0; m < 4; ++m) {
        const s16x4 bm = (m == 0) ? b0 : (m == 1) ? b1 : (m == 2) ? b2 : b3;
        s16x4 pk;
        #pragma unroll
        for (int r = 0; r < 4; ++r) {
          float e = __expf(S[4 * m + r] + bf2f(bm[r]));
          if (vbase + 8 * m + r >= VOCAB) e = 0.f;
          den += e;
          pk[r] = f2bf(e);
        }
        const uint32_t byte = (uint32_t)q * 512u
                            + (((uint32_t)(s * 64 + m * 16 + lh * 8)) ^ swzq);
        *reinterpret_cast<s16x4*>(PlB + byte) = pk;
      }
    }
    __syncthreads();  // barrier B: Pl ready

    // ---- phase 2: O^T += embT . P^T ----
    #pragma unroll
    for (int ks2 = 0; ks2 < 16; ++ks2) {
      const uint32_t voff = (uint32_t)(ks2 * 32 + lh * 16);
      const s16x8 p0 = *reinterpret_cast<const s16x8*>(PlB + (uint32_t)l31 * 512u + (voff ^ swzr));
      const s16x8 p1 = *reinterpret_cast<const s16x8*>(PlB + (uint32_t)(32 + l31) * 512u + (voff ^ swzr));
      const s16x8 ea = (ks2 == 0) ? e00 : ev[ks2 * 128];
      const s16x8 eb = (ks2 == 0) ? e01 : ev[ks2 * 128 + 64];
      Oa0 = __builtin_amdgcn_mfma_f32_32x32x16_bf16(ea, p0, Oa0, 0, 0, 0);
      Oa1 = __builtin_amdgcn_mfma_f32_32x32x16_bf16(ea, p1, Oa1, 0, 0, 0);
      Ob0 = __builtin_amdgcn_mfma_f32_32x32x16_bf16(eb, p0, Ob0, 0, 0, 0);
      Ob1 = __builtin_amdgcn_mfma_f32_32x32x16_bf16(eb, p1, Ob1, 0, 0, 0);
    }
  }

  // ---- write O partials: O[q][d], q = qth*32 + l31, d = w*64 + dt*32 + 4lh + 8m + r ----
  float* ob = o_part + ((size_t)vs * ROWS + row0) * D_MODEL;
  #pragma unroll
  for (int qth = 0; qth < 2; ++qth) {
    #pragma unroll
    for (int dt = 0; dt < 2; ++dt) {
      const f32x16& A = (qth == 0) ? (dt == 0 ? Oa0 : Ob0) : (dt == 0 ? Oa1 : Ob1);
      const size_t rowoff = (size_t)(qth * 32 + l31) * D_MODEL;
      const int dbase = w * 64 + dt * 32 + 4 * lh;
      #pragma unroll
      for (int m = 0; m < 4; ++m) {
        f32x4 v4 = { A[4 * m], A[4 * m + 1], A[4 * m + 2], A[4 * m + 3] };
        *reinterpret_cast<f32x4*>(ob + rowoff + dbase + 8 * m) = v4;
      }
    }
  }

  // ---- denom reduce (reuse Pl) ----
  __syncthreads();
  den += __shfl_xor(den, 32);
  float* red = reinterpret_cast<float*>(Pl);
  if (l < 32) red[w * 32 + l31] = den;   // w = s*2 + qt
  __syncthreads();
  if (tid < 64) {
    const int qtt = tid >> 5, col = tid & 31;
    float t = 0.f;
    #pragma unroll
    for (int s2 = 0; s2 < 8; ++s2) t += red[(s2 * 2 + qtt) * 32 + col];
    den_part[(size_t)vs * ROWS + row0 + tid] = t;
  }
}

// ---- epilogue: combine partials, residual, LayerNorm ----
__global__ __launch_bounds__(256)
void k_ln(const float* __restrict__ enc, const float* __restrict__ o_part,
          const float* __restrict__ den_part, const float* __restrict__ gam,
          const float* __restrict__ bet, float* __restrict__ out) {
  __shared__ float r1[4], r2[4];
  const int row = blockIdx.x;
  const int t = threadIdx.x;
  const int d = t * 4;
  float den = 0.f;
  #pragma unroll
  for (int p = 0; p < VS; ++p) den += den_part[(size_t)p * ROWS + row];
  const float inv = 1.f / den;
  f32x4 acc = {0.f, 0.f, 0.f, 0.f};
  #pragma unroll
  for (int p = 0; p < VS; ++p) {
    const f32x4 a = *reinterpret_cast<const f32x4*>(o_part + ((size_t)p * ROWS + row) * D_MODEL + d);
    #pragma unroll
    for (int jj = 0; jj < 4; ++jj) acc[jj] += a[jj];
  }
  const f32x4 e = *reinterpret_cast<const f32x4*>(enc + (size_t)row * D_MODEL + d);
  f32x4 y;
  #pragma unroll
  for (int jj = 0; jj < 4; ++jj) y[jj] = e[jj] + acc[jj] * inv;
  float s1 = y[0] + y[1] + y[2] + y[3];
  float s2 = y[0]*y[0] + y[1]*y[1] + y[2]*y[2] + y[3]*y[3];
  #pragma unroll
  for (int off = 1; off < 64; off <<= 1) {
    s1 += __shfl_xor(s1, off);
    s2 += __shfl_xor(s2, off);
  }
  if ((t & 63) == 0) { r1[t >> 6] = s1; r2[t >> 6] = s2; }
  __syncthreads();
  const float S1 = r1[0] + r1[1] + r1[2] + r1[3];
  const float S2 = r2[0] + r2[1] + r2[2] + r2[3];
  const float mean = S1 * (1.f / D_MODEL);
  const float var = S2 * (1.f / D_MODEL) - mean * mean;
  const float rs = rsqrtf(var + LN_EPS);
  const f32x4 gv = *reinterpret_cast<const f32x4*>(gam + d);
  const f32x4 bv = *reinterpret_cast<const f32x4*>(bet + d);
  f32x4 o;
  #pragma unroll
  for (int jj = 0; jj < 4; ++jj) o[jj] = (y[jj] - mean) * rs * gv[jj] + bv[jj];
  *reinterpret_cast<f32x4*>(out + (size_t)row * D_MODEL + d) = o;
}

extern "C" void kernel_launch(void* const* d_in, const int* in_sizes, int n_in,
                              void* d_out, int out_size, void* d_ws, size_t ws_size,
                              hipStream_t stream) {
  const float* enc = (const float*)d_in[0];
  const float* pw  = (const float*)d_in[1];
  const float* pb  = (const float*)d_in[2];
  const float* emb = (const float*)d_in[3];
  const float* gam = (const float*)d_in[4];
  const float* bet = (const float*)d_in[5];
  float* out = (float*)d_out;

  size_t off = 0;
  unsigned short* Wp = (unsigned short*)((char*)d_ws + off); off += (size_t)NTILES * 32768 * 16;  // 104.86 MB
  unsigned short* Ep = (unsigned short*)((char*)d_ws + off); off += (size_t)NTILES * 32768 * 16;  // 104.86 MB
  unsigned short* biasb = (unsigned short*)((char*)d_ws + off); off += (size_t)VP * 2;
  float* o_part = (float*)((char*)d_ws + off); off += (size_t)VS * ROWS * D_MODEL * 4;            // 67.1 MB
  float* den_part = (float*)((char*)d_ws + off); off += (size_t)VS * ROWS * 4;

  if (off > ws_size) {
    // unambiguous sentinel: ws too small -> absmax ~3.4e38
    hipMemsetAsync(d_out, 0x7f, (size_t)out_size * 4, stream);
    return;
  }

  k_pack_w<<<NTILES * 32768 / 256, 256, 0, stream>>>(pw, Wp);
  k_pack_e<<<dim3(NTILES, 32), 256, 0, stream>>>(emb, Ep);
  k_pack_bias<<<VP / 256, 256, 0, stream>>>(pb, biasb);
  k_main<<<256, 1024, 0, stream>>>(enc, biasb, Wp, Ep, o_part, den_part);
  k_ln<<<ROWS, 256, 0, stream>>>(enc, o_part, den_part, gam, bet, out);
}